// Round 4
// baseline (292.184 us; speedup 1.0000x reference)
//
#include <hip/hip_runtime.h>

#define N_ 8192
#define D_ 256

typedef short short8 __attribute__((ext_vector_type(8)));
typedef unsigned short u16x8 __attribute__((ext_vector_type(8)));
typedef float f32x4 __attribute__((ext_vector_type(4)));

__device__ __forceinline__ unsigned short f2bf(float f) {
    union { float f; unsigned u; } v; v.f = f;
    unsigned r = v.u + 0x7FFFu + ((v.u >> 16) & 1u);
    return (unsigned short)(r >> 16);
}
__device__ __forceinline__ float bf2f(unsigned short h) {
    union { unsigned u; float f; } v; v.u = ((unsigned)h) << 16;
    return v.f;
}

// ---------------------------------------------------------------------------
// kA: per block, 8 rows i0..i0+7:
//   dis_i = rsqrt(rowsum(A_i) + 2)          (streams 8 rows of A)
//   P[i][c] = dot(X[i,:], W[c,:])           (pure VALU, X tile in LDS)
//   Corr[i][c] = bf16(2*dis_i^2*P + b[c])
//   Zt[c][i]   = bf16(dis_i*P)              (column-major Z for kB's B-operand)
// ---------------------------------------------------------------------------
__global__ __launch_bounds__(256) void kA(
    const float* __restrict__ A, const float* __restrict__ X,
    const float* __restrict__ W, const float* __restrict__ bv,
    unsigned short* __restrict__ Corr, unsigned short* __restrict__ Zt)
{
    __shared__ float sX[8][256];   // 8 KB
    __shared__ float red[8][32];   // 1 KB
    __shared__ float disS[8];

    const int t = threadIdx.x;
    const int i0 = blockIdx.x * 8;

    // ---- phase 1: rowsums of A rows (32 lanes per row) ----
    {
        const int r = t >> 5, g = t & 31;
        const float4* Ar = (const float4*)(A + (size_t)(i0 + r) * N_);
        float s = 0.f;
        #pragma unroll 4
        for (int ch = 0; ch < 64; ++ch) {     // 64 * 32 lanes * 4 floats = 8192
            float4 v = Ar[ch * 32 + g];
            s += (v.x + v.y) + (v.z + v.w);
        }
        red[r][g] = s;
    }
    // ---- stage X tile 8x256 f32 ----
    {
        const int xr = t >> 5, xc = (t & 31) * 8;
        const float* src = X + (size_t)(i0 + xr) * D_ + xc;
        float4 v0 = *(const float4*)(src);
        float4 v1 = *(const float4*)(src + 4);
        *(float4*)&sX[xr][xc]     = v0;
        *(float4*)&sX[xr][xc + 4] = v1;
    }
    __syncthreads();
    if (t < 8) {
        float v = 0.f;
        #pragma unroll
        for (int j = 0; j < 32; ++j) v += red[t][j];
        disS[t] = rsqrtf(v + 2.0f);
    }
    __syncthreads();

    // ---- phase 2: thread t owns output column c = t ----
    const int c = t;
    float acc8[8];
    #pragma unroll
    for (int rr = 0; rr < 8; ++rr) acc8[rr] = 0.f;

    const float4* Wr = (const float4*)(W + (size_t)c * D_);
    for (int k4 = 0; k4 < 64; ++k4) {
        const float4 wv = Wr[k4];
        #pragma unroll
        for (int rr = 0; rr < 8; ++rr) {
            const float4 xv = *(const float4*)&sX[rr][k4 * 4];
            acc8[rr] += xv.x * wv.x + xv.y * wv.y + xv.z * wv.z + xv.w * wv.w;
        }
    }

    const float bc = bv[c];
    u16x8 zcol;
    #pragma unroll
    for (int rr = 0; rr < 8; ++rr) {
        const float p = acc8[rr];
        const float dv = disS[rr];
        Corr[(size_t)(i0 + rr) * D_ + c] = f2bf(2.0f * dv * dv * p + bc);
        zcol[rr] = f2bf(dv * p);
    }
    *(u16x8*)(Zt + (size_t)c * N_ + i0) = zcol;   // 16B aligned (i0 % 8 == 0)
}

// ---------------------------------------------------------------------------
// kB: out[i][c] = relu( dis_i * (A @ Z)[i][c] + Corr[i][c] )   -- out is F32
// dis_i recomputed in-kernel from the A values already streamed (0 extra HBM).
// 512 threads = 8 waves, each wave owns a 32x32 output tile. BM=32, BK=32,
// single LDS buffer (23 KB), register prefetch.
// ---------------------------------------------------------------------------
__global__ __launch_bounds__(512) void kB(
    const float* __restrict__ A, const unsigned short* __restrict__ Corr,
    const unsigned short* __restrict__ Zt, float* __restrict__ out)
{
    __shared__ unsigned short sA[32][40];    // 32 bf16 + pad, 2.5 KB
    __shared__ unsigned short sB[256][40];   // 20.5 KB
    __shared__ float rsS[32];

    const int t = threadIdx.x;
    const int lane = t & 63, wid = t >> 6;
    const int m0 = blockIdx.x * 32;
    const int bn = wid * 32;

    const int a_r = t >> 4, a_c2 = t & 15;   // A stage: row, 2-f32 chunk
    const int b_r = t >> 1, b_h = t & 1;     // B stage: row, 16-u16 half

    const float*          Ap = A  + (size_t)(m0 + a_r) * N_ + a_c2 * 2;
    const unsigned short* Bp = Zt + (size_t)b_r * N_ + b_h * 16;

    f32x4 acc[2][2];
    #pragma unroll
    for (int m = 0; m < 2; ++m)
        #pragma unroll
        for (int n = 0; n < 2; ++n) acc[m][n] = (f32x4){0.f, 0.f, 0.f, 0.f};
    float rsum = 0.f;

    // prologue: chunk 0
    {
        float2 av = *(const float2*)(Ap);
        u16x8 v0 = *(const u16x8*)(Bp);
        u16x8 v1 = *(const u16x8*)(Bp + 8);
        sA[a_r][a_c2 * 2]     = f2bf(av.x);
        sA[a_r][a_c2 * 2 + 1] = f2bf(av.y);
        *(u16x8*)&sB[b_r][b_h * 16]     = v0;
        *(u16x8*)&sB[b_r][b_h * 16 + 8] = v1;
        rsum += av.x + av.y;
    }
    __syncthreads();

    const int NT = N_ / 32;   // 256 K-chunks
    for (int ts = 0; ts < NT; ++ts) {
        const bool pf = (ts + 1 < NT);
        float2 av; u16x8 nb0, nb1;
        if (pf) {   // prefetch next chunk to registers (hides under MFMA+barrier)
            const int k0 = (ts + 1) * 32;
            av  = *(const float2*)(Ap + k0);
            nb0 = *(const u16x8*)(Bp + k0);
            nb1 = *(const u16x8*)(Bp + k0 + 8);
        }
        short8 af[2], bq[2];
        #pragma unroll
        for (int mf = 0; mf < 2; ++mf)
            af[mf] = *(const short8*)&sA[mf * 16 + (lane & 15)][(lane >> 4) * 8];
        #pragma unroll
        for (int nf = 0; nf < 2; ++nf)
            bq[nf] = *(const short8*)&sB[bn + nf * 16 + (lane & 15)][(lane >> 4) * 8];
        #pragma unroll
        for (int mf = 0; mf < 2; ++mf)
            #pragma unroll
            for (int nf = 0; nf < 2; ++nf)
                acc[mf][nf] = __builtin_amdgcn_mfma_f32_16x16x32_bf16(
                    af[mf], bq[nf], acc[mf][nf], 0, 0, 0);
        __syncthreads();   // everyone done reading current LDS tile
        if (pf) {
            sA[a_r][a_c2 * 2]     = f2bf(av.x);
            sA[a_r][a_c2 * 2 + 1] = f2bf(av.y);
            *(u16x8*)&sB[b_r][b_h * 16]     = nb0;
            *(u16x8*)&sB[b_r][b_h * 16 + 8] = nb1;
            rsum += av.x + av.y;
        }
        __syncthreads();   // next tile visible
    }

    // reduce rowsums: 16 consecutive lanes share a row
    rsum += __shfl_down(rsum, 8, 16);
    rsum += __shfl_down(rsum, 4, 16);
    rsum += __shfl_down(rsum, 2, 16);
    rsum += __shfl_down(rsum, 1, 16);
    if ((t & 15) == 0) rsS[a_r] = rsum;
    __syncthreads();

    // epilogue — F32 output
    #pragma unroll
    for (int mf = 0; mf < 2; ++mf)
        #pragma unroll
        for (int r = 0; r < 4; ++r) {
            const int il = mf * 16 + ((lane >> 4) << 2) + r;
            const int i = m0 + il;
            const float dv = rsqrtf(rsS[il] + 2.0f);
            #pragma unroll
            for (int nf = 0; nf < 2; ++nf) {
                const int c = bn + nf * 16 + (lane & 15);
                const float x = dv * acc[mf][nf][r] + bf2f(Corr[(size_t)i * D_ + c]);
                out[(size_t)i * D_ + c] = fmaxf(x, 0.f);
            }
        }
}

extern "C" void kernel_launch(void* const* d_in, const int* in_sizes, int n_in,
                              void* d_out, int out_size, void* d_ws, size_t ws_size,
                              hipStream_t stream) {
    (void)in_sizes; (void)n_in; (void)out_size; (void)ws_size;
    const float* X = (const float*)d_in[0];
    const float* A = (const float*)d_in[1];
    const float* W = (const float*)d_in[2];
    const float* b = (const float*)d_in[3];
    float* outp = (float*)d_out;          // reference output dtype is FLOAT32

    unsigned short* Corr = (unsigned short*)d_ws;            // 4 MB
    unsigned short* Zt   = Corr + (size_t)N_ * D_;           // 4 MB

    kA<<<N_ / 8, 256, 0, stream>>>(A, X, W, b, Corr, Zt);
    kB<<<N_ / 32, 512, 0, stream>>>(A, Corr, Zt, outp);
}

// Round 5
// 211.477 us; speedup vs baseline: 1.3816x; 1.3816x over previous
//
#include <hip/hip_runtime.h>

#define N_ 8192
#define D_ 256

typedef short short8 __attribute__((ext_vector_type(8)));
typedef unsigned short u16x4 __attribute__((ext_vector_type(4)));
typedef unsigned short u16x8 __attribute__((ext_vector_type(8)));
typedef float f32x4 __attribute__((ext_vector_type(4)));

__device__ __forceinline__ unsigned short f2bf(float f) {
    union { float f; unsigned u; } v; v.f = f;
    unsigned r = v.u + 0x7FFFu + ((v.u >> 16) & 1u);
    return (unsigned short)(r >> 16);
}
__device__ __forceinline__ float bf2f(unsigned short h) {
    union { unsigned u; float f; } v; v.u = ((unsigned)h) << 16;
    return v.f;
}

// ---------------- K1: disK[r] = rsqrt(rowsum(A_r) + 2) ----------------------
// Pure HBM stream: 2048 blocks x 4 waves, one wave per row.
__global__ __launch_bounds__(256) void k_dis(const float* __restrict__ A,
                                             float* __restrict__ disK) {
    const int w = threadIdx.x >> 6, l = threadIdx.x & 63;
    const int row = blockIdx.x * 4 + w;
    const float4* Ar = (const float4*)(A + (size_t)row * N_);
    float s = 0.f;
    #pragma unroll 8
    for (int i = l; i < N_ / 4; i += 64) {
        float4 v = Ar[i];
        s += (v.x + v.y) + (v.z + v.w);
    }
    #pragma unroll
    for (int o = 32; o; o >>= 1) s += __shfl_down(s, o);
    if (l == 0) disK[row] = rsqrtf(s + 2.0f);
}

// ---------------- K2: P = X@W^T ; Corr = 2*dis^2*P + b ; Zt = P^T (plain) ---
__global__ __launch_bounds__(256) void k_P(
    const float* __restrict__ X, const float* __restrict__ W,
    const float* __restrict__ bv, const float* __restrict__ disK,
    unsigned short* __restrict__ Corr, unsigned short* __restrict__ Zt)
{
    __shared__ float sX[8][256];
    const int t = threadIdx.x;
    const int i0 = blockIdx.x * 8;

    {   // stage X rows i0..i0+7
        const int xr = t >> 5, xc = (t & 31) * 8;
        const float* src = X + (size_t)(i0 + xr) * D_ + xc;
        *(float4*)&sX[xr][xc]     = *(const float4*)(src);
        *(float4*)&sX[xr][xc + 4] = *(const float4*)(src + 4);
    }
    __syncthreads();

    const int c = t;
    float acc8[8];
    #pragma unroll
    for (int rr = 0; rr < 8; ++rr) acc8[rr] = 0.f;
    const float4* Wr = (const float4*)(W + (size_t)c * D_);
    for (int k4 = 0; k4 < 64; ++k4) {
        const float4 wv = Wr[k4];
        #pragma unroll
        for (int rr = 0; rr < 8; ++rr) {
            const float4 xv = *(const float4*)&sX[rr][k4 * 4];
            acc8[rr] += xv.x * wv.x + xv.y * wv.y + xv.z * wv.z + xv.w * wv.w;
        }
    }
    const float bc = bv[c];
    u16x8 zcol;
    #pragma unroll
    for (int rr = 0; rr < 8; ++rr) {
        const float p = acc8[rr];
        const float dv = disK[i0 + rr];
        Corr[(size_t)(i0 + rr) * D_ + c] = f2bf(2.0f * dv * dv * p + bc);
        zcol[rr] = f2bf(p);                         // plain P — dis folded into kB's A-stage
    }
    *(u16x8*)(Zt + (size_t)c * N_ + i0) = zcol;
}

#define KBAR() do {                                             \
    asm volatile("s_waitcnt lgkmcnt(0)" ::: "memory");          \
    __builtin_amdgcn_sched_barrier(0);                          \
    __builtin_amdgcn_s_barrier();                               \
    __builtin_amdgcn_sched_barrier(0);                          \
} while (0)

// ---------------- K3: out = relu(dis_i * sum_k A[i][k]*dis_k*P[k][c] + Corr) -
// 256 blocks x 512 thr. A (scaled by dis_k) double-buffered in LDS, BK=64,
// 2-iter-deep register prefetch; B straight global->reg (L2-resident Zt);
// raw s_barrier + lgkmcnt(0) only — vmcnt prefetch never drained.
__global__ __launch_bounds__(512) void kB(
    const float* __restrict__ A, const float* __restrict__ disK,
    const unsigned short* __restrict__ Corr, const unsigned short* __restrict__ Zt,
    float* __restrict__ out)
{
    __shared__ unsigned short sA[2][32][72];   // 9.2 KB, pad->read-conflict-free

    const int t = threadIdx.x, lane = t & 63, wid = t >> 6;
    const int m0 = blockIdx.x * 32, bn = wid * 32;

    const int sr = t >> 4, scq = t & 15;       // staging: row, float4-chunk
    const float4* Ast = (const float4*)(A + (size_t)(m0 + sr) * N_) + scq;
    const float4* Dst = (const float4*)disK + scq;
    const unsigned short* Bq0 = Zt + (size_t)(bn + (lane & 15)) * N_ + (lane >> 4) * 8;
    const unsigned short* Bq1 = Bq0 + (size_t)16 * N_;

    f32x4 acc[2][2];
    #pragma unroll
    for (int m = 0; m < 2; ++m)
        #pragma unroll
        for (int n = 0; n < 2; ++n) acc[m][n] = (f32x4){0.f, 0.f, 0.f, 0.f};

    auto stage = [&](unsigned short (*buf)[72], float4 av, float4 dv) {
        u16x4 h;
        h[0] = f2bf(av.x * dv.x); h[1] = f2bf(av.y * dv.y);
        h[2] = f2bf(av.z * dv.z); h[3] = f2bf(av.w * dv.w);
        *(u16x4*)&buf[sr][scq * 4] = h;
    };
    auto loadB = [&](int ts, short8 (&bq)[2][2]) {
        const int k0 = ts * 64;
        bq[0][0] = *(const short8*)(Bq0 + k0);
        bq[0][1] = *(const short8*)(Bq0 + k0 + 32);
        bq[1][0] = *(const short8*)(Bq1 + k0);
        bq[1][1] = *(const short8*)(Bq1 + k0 + 32);
    };
    auto comp = [&](unsigned short (*buf)[72], short8 (&bq)[2][2]) {
        short8 af[2][2];
        #pragma unroll
        for (int mf = 0; mf < 2; ++mf)
            #pragma unroll
            for (int kk = 0; kk < 2; ++kk)
                af[mf][kk] = *(const short8*)&buf[mf * 16 + (lane & 15)]
                                                [kk * 32 + (lane >> 4) * 8];
        #pragma unroll
        for (int kk = 0; kk < 2; ++kk)
            #pragma unroll
            for (int mf = 0; mf < 2; ++mf)
                #pragma unroll
                for (int nf = 0; nf < 2; ++nf)
                    acc[mf][nf] = __builtin_amdgcn_mfma_f32_16x16x32_bf16(
                        af[mf][kk], bq[nf][kk], acc[mf][nf], 0, 0, 0);
    };

    float4 aA, aB, dA, dB;
    short8 bC[2][2], bN[2][2];

    // prologue: LDS buf0 = A(0)*dis; aA=A(1), aB=A(2); bC=B(0)
    {
        float4 l0 = Ast[0], d0 = Dst[0];
        aA = Ast[16]; dA = Dst[16];
        aB = Ast[32]; dB = Dst[32];
        loadB(0, bC);
        stage(sA[0], l0, d0);
        KBAR();
    }

    for (int t2 = 0; t2 < 64; ++t2) {
        const int ts = t2 * 2;
        // step A: compute ts (buf0, B=bC); stage A(ts+1)->buf1
        stage(sA[1], aA, dA);
        { const int ka = min(ts + 3, 127); aA = Ast[ka * 16]; dA = Dst[ka * 16]; }
        loadB(min(ts + 1, 127), bN);
        comp(sA[0], bC);
        KBAR();
        // step B: compute ts+1 (buf1, B=bN); stage A(ts+2)->buf0
        stage(sA[0], aB, dB);
        { const int kb = min(ts + 4, 127); aB = Ast[kb * 16]; dB = Dst[kb * 16]; }
        loadB(min(ts + 2, 127), bC);
        comp(sA[1], bN);
        KBAR();
    }

    // epilogue — F32 output
    #pragma unroll
    for (int mf = 0; mf < 2; ++mf)
        #pragma unroll
        for (int r = 0; r < 4; ++r) {
            const int i = m0 + mf * 16 + ((lane >> 4) << 2) + r;
            const float dv = disK[i];
            #pragma unroll
            for (int nf = 0; nf < 2; ++nf) {
                const int c = bn + nf * 16 + (lane & 15);
                const float x = dv * acc[mf][nf][r] + bf2f(Corr[(size_t)i * D_ + c]);
                out[(size_t)i * D_ + c] = fmaxf(x, 0.f);
            }
        }
}

extern "C" void kernel_launch(void* const* d_in, const int* in_sizes, int n_in,
                              void* d_out, int out_size, void* d_ws, size_t ws_size,
                              hipStream_t stream) {
    (void)in_sizes; (void)n_in; (void)out_size; (void)ws_size;
    const float* X = (const float*)d_in[0];
    const float* A = (const float*)d_in[1];
    const float* W = (const float*)d_in[2];
    const float* b = (const float*)d_in[3];
    float* outp = (float*)d_out;

    float* disK = (float*)d_ws;                                     // 32 KB
    unsigned short* Corr = (unsigned short*)((char*)d_ws + 32768);  // 4 MB
    unsigned short* Zt   = Corr + (size_t)N_ * D_;                  // 4 MB

    k_dis<<<N_ / 4, 256, 0, stream>>>(A, disK);
    k_P<<<N_ / 8, 256, 0, stream>>>(X, W, b, disK, Corr, Zt);
    kB<<<N_ / 32, 512, 0, stream>>>(A, disK, Corr, Zt, outp);
}